// Round 1
// baseline (712.103 us; speedup 1.0000x reference)
//
#include <hip/hip_runtime.h>

// VoxelHashTableFlowTraverse: 8-corner hash-grid lookup + trilinear blend.
// Layout: 32 lanes per query; lane c in [0,30) owns float4 chunk c of the
// 120-float feature row. Feature gathers and output stores are coalesced
// 480B contiguous runs; hash-table probes are same-address within the
// 32-lane group (single transaction + broadcast).

#define TABLE_MASK ((1u << 20) - 1u)
#define FEAT_DIM 120

__global__ __launch_bounds__(256) void voxel_trilinear_kernel(
    const float* __restrict__ qp,      // [M,3]
    const float* __restrict__ feat,    // [n_vox,120]
    const int*   __restrict__ table,   // [2^20]
    float*       __restrict__ out,     // [M,120]
    int M)
{
    const int gid = blockIdx.x * blockDim.x + threadIdx.x;
    const int q = gid >> 5;        // query index
    const int c = gid & 31;        // float4 chunk index within feature row
    if (q >= M) return;

    // Query point (broadcast load: all 32 lanes same address)
    const float px = qp[q * 3 + 0];
    const float py = qp[q * 3 + 1];
    const float pz = qp[q * 3 + 2];

    // Grid coords: must use division by 0.1f to match reference rounding.
    const float gx = px / 0.1f;
    const float gy = py / 0.1f;
    const float gz = pz / 0.1f;
    const float flx = floorf(gx), fly = floorf(gy), flz = floorf(gz);
    const float rx = gx - flx, ry = gy - fly, rz = gz - flz;
    const int bx = (int)flx, by = (int)fly, bz = (int)flz;

    const bool active = (c < 30);

    float4 acc = make_float4(0.f, 0.f, 0.f, 0.f);

    // Same corner order as reference.
    const int CX[8] = {0, 1, 0, 0, 1, 1, 0, 1};
    const int CY[8] = {0, 0, 1, 0, 1, 0, 1, 1};
    const int CZ[8] = {0, 0, 0, 1, 0, 1, 1, 1};

#pragma unroll
    for (int k = 0; k < 8; ++k) {
        const int cx = CX[k], cy = CY[k], cz = CZ[k];
        // Wrapping uint32 hash, masked to low 20 bits (TABLE is 2^20).
        unsigned int h = (unsigned int)(bx + cx) * 73856093u
                       + (unsigned int)(by + cy) * 19349669u
                       + (unsigned int)(bz + cz) * 83492791u;
        h &= TABLE_MASK;
        const int vidx = table[h];   // broadcast within 32-lane group

        if (vidx >= 0 && active) {
            const float wx = cx ? rx : (1.0f - rx);
            const float wy = cy ? ry : (1.0f - ry);
            const float wz = cz ? rz : (1.0f - rz);
            const float w = wx * wy * wz;
            const float4 f = *reinterpret_cast<const float4*>(
                feat + (size_t)vidx * FEAT_DIM + c * 4);
            acc.x += f.x * w;
            acc.y += f.y * w;
            acc.z += f.z * w;
            acc.w += f.w * w;
        }
    }

    if (active) {
        *reinterpret_cast<float4*>(out + (size_t)q * FEAT_DIM + c * 4) = acc;
    }
}

extern "C" void kernel_launch(void* const* d_in, const int* in_sizes, int n_in,
                              void* d_out, int out_size, void* d_ws, size_t ws_size,
                              hipStream_t stream) {
    const float* qp    = (const float*)d_in[0];
    const float* feat  = (const float*)d_in[1];
    const int*   table = (const int*)d_in[2];
    float*       out   = (float*)d_out;

    const int M = in_sizes[0] / 3;                  // number of queries
    const long long threads = (long long)M * 32;    // 32 lanes per query
    const int block = 256;
    const int grid = (int)((threads + block - 1) / block);

    voxel_trilinear_kernel<<<grid, block, 0, stream>>>(qp, feat, table, out, M);
}